// Round 5
// baseline (219.413 us; speedup 1.0000x reference)
//
#include <hip/hip_runtime.h>
#include <hip/hip_bf16.h>
#include <math.h>

#define N_NODES 8192
#define F_IN    512
#define C_OUT   128
#define CSR_CAP 128
#define NEG_SLOPE 0.2f

typedef float f4v __attribute__((ext_vector_type(4)));

// ---------------------------------------------------------------------------
// Kernel A: adjacency -> CSR (u16 cols, cap 128) + per-row counts.
// One WAVE per row. Zero barriers, zero LDS. Pure HBM stream + light VALU.
// [byte-identical to round 4 — launched 3x this round as a timing probe]
// ---------------------------------------------------------------------------
__device__ __forceinline__ int lane_lt_popc(unsigned long long m) {
  return __builtin_amdgcn_mbcnt_hi((unsigned)(m >> 32),
         __builtin_amdgcn_mbcnt_lo((unsigned)m, 0u));
}

__global__ void __launch_bounds__(512) adj_scan_kernel(
    const float* __restrict__ adj, int* __restrict__ counts,
    unsigned short* __restrict__ elist)
{
  const int lane = threadIdx.x & 63;
  const int wv   = threadIdx.x >> 6;
  const int row  = blockIdx.x * 8 + wv;
  const f4v* rp  = (const f4v*)(adj + (size_t)row * N_NODES);
  unsigned short* er = elist + (size_t)row * CSR_CAP;

  int base = 0;
  for (int cb = 0; cb < 32; cb += 8) {
    f4v v[8];
    #pragma unroll
    for (int q = 0; q < 8; ++q)
      v[q] = __builtin_nontemporal_load(&rp[(cb + q) * 64 + lane]);
    #pragma unroll
    for (int q = 0; q < 8; ++q) {
      const int colb = (cb + q) * 256 + lane * 4;
      unsigned long long b0 = __ballot(v[q][0] != 0.f);
      unsigned long long b1 = __ballot(v[q][1] != 0.f);
      unsigned long long b2 = __ballot(v[q][2] != 0.f);
      unsigned long long b3 = __ballot(v[q][3] != 0.f);
      int o = base + lane_lt_popc(b0) + lane_lt_popc(b1)
                   + lane_lt_popc(b2) + lane_lt_popc(b3);
      if ((b0 >> lane) & 1ull) { if (o < CSR_CAP) er[o] = (unsigned short)(colb + 0); ++o; }
      if ((b1 >> lane) & 1ull) { if (o < CSR_CAP) er[o] = (unsigned short)(colb + 1); ++o; }
      if ((b2 >> lane) & 1ull) { if (o < CSR_CAP) er[o] = (unsigned short)(colb + 2); ++o; }
      if ((b3 >> lane) & 1ull) { if (o < CSR_CAP) er[o] = (unsigned short)(colb + 3); ++o; }
      base += __popcll(b0) + __popcll(b1) + __popcll(b2) + __popcll(b3);
    }
  }
  if (lane == 0) counts[row] = base < CSR_CAP ? base : CSR_CAP;
}

// ---------------------------------------------------------------------------
// Kernel 1: ft = X @ W fused with asrc/adst dots + per-block col-sums.
// [byte-identical to round 4]
// ---------------------------------------------------------------------------
__global__ void __launch_bounds__(512) gemm_ft_kernel(
    const float* __restrict__ X, const float* __restrict__ W,
    const float* __restrict__ att_src, const float* __restrict__ att_dst,
    float* __restrict__ ft, float* __restrict__ asrc, float* __restrict__ adst,
    float* __restrict__ Spart)
{
  __shared__ float sx[32][36];
  __shared__ float sk[32][132];

  const int tid  = threadIdx.x;
  const int row0 = blockIdx.x * 32;
  const int rg   = tid >> 6;
  const int r0   = rg * 4;
  const int c0   = (tid & 63) * 2;
  const int lane = tid & 63;

  float acc[4][2] = {};

  for (int kt = 0; kt < F_IN; kt += 32) {
    if (tid < 256) {
      int row = tid >> 3, kv = (tid & 7) * 4;
      f4v v = *(const f4v*)(X + (size_t)(row0 + row) * F_IN + kt + kv);
      *(f4v*)&sx[row][kv] = v;
    }
    #pragma unroll
    for (int q = 0; q < 2; ++q) {
      int idx = q * 512 + tid;
      int kk  = idx >> 5;
      int cc  = (idx & 31) * 4;
      *(f4v*)&sk[kk][cc] = *(const f4v*)(W + (size_t)(kt + kk) * C_OUT + cc);
    }
    __syncthreads();
    #pragma unroll
    for (int k = 0; k < 32; k += 4) {
      f4v a[4];
      float2 b[4];
      #pragma unroll
      for (int q = 0; q < 4; ++q) a[q] = *(const f4v*)&sx[r0 + q][k];
      #pragma unroll
      for (int q = 0; q < 4; ++q) b[q] = *(const float2*)&sk[k + q][c0];
      #pragma unroll
      for (int i = 0; i < 4; ++i) {
        acc[i][0] += a[i][0] * b[0].x; acc[i][1] += a[i][0] * b[0].y;
        acc[i][0] += a[i][1] * b[1].x; acc[i][1] += a[i][1] * b[1].y;
        acc[i][0] += a[i][2] * b[2].x; acc[i][1] += a[i][2] * b[2].y;
        acc[i][0] += a[i][3] * b[3].x; acc[i][1] += a[i][3] * b[3].y;
      }
    }
    __syncthreads();
  }

  #pragma unroll
  for (int i = 0; i < 4; ++i)
    *(float2*)(ft + (size_t)(row0 + r0 + i) * C_OUT + c0) =
        make_float2(acc[i][0], acc[i][1]);

  float2 as = *(const float2*)(att_src + c0);
  float2 ad = *(const float2*)(att_dst + c0);
  #pragma unroll
  for (int i = 0; i < 4; ++i) {
    float ps = acc[i][0] * as.x + acc[i][1] * as.y;
    float pd = acc[i][0] * ad.x + acc[i][1] * ad.y;
    #pragma unroll
    for (int off = 32; off > 0; off >>= 1) {
      ps += __shfl_xor(ps, off);
      pd += __shfl_xor(pd, off);
    }
    if (lane == 0) {
      asrc[row0 + r0 + i] = ps;
      adst[row0 + r0 + i] = pd;
    }
  }

  float* scp = &sx[0][0];
  float s0 = acc[0][0] + acc[1][0] + acc[2][0] + acc[3][0];
  float s1 = acc[0][1] + acc[1][1] + acc[2][1] + acc[3][1];
  *(float2*)&scp[rg * 128 + c0] = make_float2(s0, s1);
  __syncthreads();
  if (tid < 128) {
    float s = 0.f;
    #pragma unroll
    for (int q = 0; q < 8; ++q) s += scp[q * 128 + tid];
    Spart[(size_t)blockIdx.x * 128 + tid] = s;
  }
}

// ---------------------------------------------------------------------------
// Kernel 2: S[c] = sum over 256 block partials
// ---------------------------------------------------------------------------
__global__ void colsum2_kernel(const float* __restrict__ Spart,
                               float* __restrict__ S)
{
  __shared__ float r2[128];
  const int t = threadIdx.x;
  const int c = t & 127, h = t >> 7;
  float s = 0.f;
  for (int b = h * 128; b < h * 128 + 128; ++b) s += Spart[(size_t)b * 128 + c];
  if (h) r2[c] = s;
  __syncthreads();
  if (!h) S[c] = s + r2[c];
}

// ---------------------------------------------------------------------------
// Kernel B: softmax + gather from CSR. [byte-identical to round 4]
// ---------------------------------------------------------------------------
__global__ void __launch_bounds__(512) gat_gather_kernel(
    const int* __restrict__ counts, const unsigned short* __restrict__ elist,
    const float* __restrict__ ft, const float* __restrict__ asrc,
    const float* __restrict__ adst, const float* __restrict__ S,
    float* __restrict__ out)
{
  __shared__ int   sj[8][CSR_CAP];
  __shared__ float sw[8][CSR_CAP];

  const int lane = threadIdx.x & 63;
  const int wv   = threadIdx.x >> 6;
  const int row  = blockIdx.x * 8 + wv;
  const int cnt  = counts[row];
  const float ai = asrc[row];
  const unsigned short* er = elist + (size_t)row * CSR_CAP;

  float dsum = 0.f;
  for (int e = lane; e < cnt; e += 64) {
    int j = er[e];
    float s = ai + adst[j];
    float l = s < 0.f ? NEG_SLOPE * s : s;
    float w = expf(l);
    sj[wv][e] = j;
    sw[wv][e] = w - 1.0f;
    dsum += w;
  }
  #pragma unroll
  for (int off = 32; off > 0; off >>= 1) dsum += __shfl_xor(dsum, off);
  const float denom = (float)(N_NODES - cnt) + dsum;

  __syncthreads();

  float2 acc = make_float2(0.f, 0.f);
  const float2* ft2 = (const float2*)ft;
  int e = 0;
  for (; e + 4 <= cnt; e += 4) {
    int   j0 = sj[wv][e+0], j1 = sj[wv][e+1], j2 = sj[wv][e+2], j3 = sj[wv][e+3];
    float w0 = sw[wv][e+0], w1 = sw[wv][e+1], w2 = sw[wv][e+2], w3 = sw[wv][e+3];
    float2 f0 = ft2[(size_t)j0 * 64 + lane];
    float2 f1 = ft2[(size_t)j1 * 64 + lane];
    float2 f2 = ft2[(size_t)j2 * 64 + lane];
    float2 f3 = ft2[(size_t)j3 * 64 + lane];
    acc.x += w0 * f0.x; acc.y += w0 * f0.y;
    acc.x += w1 * f1.x; acc.y += w1 * f1.y;
    acc.x += w2 * f2.x; acc.y += w2 * f2.y;
    acc.x += w3 * f3.x; acc.y += w3 * f3.y;
  }
  for (; e < cnt; ++e) {
    int   j = sj[wv][e];
    float w = sw[wv][e];
    float2 f = ft2[(size_t)j * 64 + lane];
    acc.x += w * f.x; acc.y += w * f.y;
  }

  float2 sv = ((const float2*)S)[lane];
  float ox = (sv.x + acc.x) / denom;
  float oy = (sv.y + acc.y) / denom;
  ox = ox > 0.f ? ox : expm1f(ox);
  oy = oy > 0.f ? oy : expm1f(oy);
  ((float2*)out)[(size_t)row * 64 + lane] = make_float2(ox, oy);
}

// ---------------------------------------------------------------------------
// ATTRIBUTION PROBE: adj_scan launched 3x (idempotent -> identical output).
//   dur5 - dur4 = 2 * (T_adj + launch_overhead)
// ---------------------------------------------------------------------------
extern "C" void kernel_launch(void* const* d_in, const int* in_sizes, int n_in,
                              void* d_out, int out_size, void* d_ws, size_t ws_size,
                              hipStream_t stream)
{
  const float* X       = (const float*)d_in[0];   // features 8192x512
  const float* adj     = (const float*)d_in[1];   // adjacency 8192x8192
  const float* W       = (const float*)d_in[2];   // kernel 512x128
  const float* att_src = (const float*)d_in[3];   // 128
  const float* att_dst = (const float*)d_in[4];   // 128
  float* out = (float*)d_out;

  float* ws    = (float*)d_ws;
  float* ft    = ws;                                   // 8192*128
  float* asrc  = ft + (size_t)N_NODES * C_OUT;         // 8192
  float* adst  = asrc + N_NODES;                       // 8192
  float* Spart = adst + N_NODES;                       // 256*128
  float* S     = Spart + 256 * 128;                    // 128
  int*   counts = (int*)(S + 128);                     // 8192
  unsigned short* elist = (unsigned short*)(counts + N_NODES); // 8192*128 u16

  adj_scan_kernel<<<N_NODES / 8, 512, 0, stream>>>(adj, counts, elist);
  adj_scan_kernel<<<N_NODES / 8, 512, 0, stream>>>(adj, counts, elist);
  adj_scan_kernel<<<N_NODES / 8, 512, 0, stream>>>(adj, counts, elist);
  gemm_ft_kernel<<<N_NODES / 32, 512, 0, stream>>>(X, W, att_src, att_dst,
                                                   ft, asrc, adst, Spart);
  colsum2_kernel<<<1, 256, 0, stream>>>(Spart, S);
  gat_gather_kernel<<<N_NODES / 8, 512, 0, stream>>>(counts, elist, ft,
                                                     asrc, adst, S, out);
}

// Round 6
// 99.593 us; speedup vs baseline: 2.2031x; 2.2031x over previous
//
#include <hip/hip_runtime.h>
#include <hip/hip_bf16.h>
#include <math.h>

#define N_NODES 8192
#define F_IN    512
#define C_OUT   128
#define CSR_CAP 128
#define NEG_SLOPE 0.2f

typedef float f4v __attribute__((ext_vector_type(4)));

__device__ __forceinline__ int lane_lt_popc(unsigned long long m) {
  return __builtin_amdgcn_mbcnt_hi((unsigned)(m >> 32),
         __builtin_amdgcn_mbcnt_lo((unsigned)m, 0u));
}

// ---------------------------------------------------------------------------
// FAT kernel: 1280 blocks of 512 threads.
//   bid % 5 == 4  -> gemm role (256 blocks): ft = X@W + asrc/adst + Spart
//   else          -> adj role (1024 blocks): adjacency -> CSR(u16) + counts
// Roles are independent; interleaving lets the BW-bound adjacency stream hide
// the gemm's VALU + load latency (adj: ~44 us of HBM stream with ~5% VALU).
// ---------------------------------------------------------------------------
__global__ void __launch_bounds__(512) fat_kernel(
    const float* __restrict__ adj, int* __restrict__ counts,
    unsigned short* __restrict__ elist,
    const float* __restrict__ X, const float* __restrict__ W,
    const float* __restrict__ att_src, const float* __restrict__ att_dst,
    float* __restrict__ ft, float* __restrict__ asrc, float* __restrict__ adst,
    float* __restrict__ Spart)
{
  __shared__ float sx[32][36];
  __shared__ float sk[32][132];

  const int bid = blockIdx.x;
  const int tid = threadIdx.x;

  if ((bid % 5) == 4) {
    // ---------------- gemm role ----------------
    const int gb   = bid / 5;              // 0..255
    const int row0 = gb * 32;
    const int rg   = tid >> 6;
    const int r0   = rg * 4;
    const int c0   = (tid & 63) * 2;
    const int lane = tid & 63;

    float acc[4][2] = {};

    for (int kt = 0; kt < F_IN; kt += 32) {
      if (tid < 256) {
        int row = tid >> 3, kv = (tid & 7) * 4;
        f4v v = *(const f4v*)(X + (size_t)(row0 + row) * F_IN + kt + kv);
        *(f4v*)&sx[row][kv] = v;
      }
      #pragma unroll
      for (int q = 0; q < 2; ++q) {
        int idx = q * 512 + tid;
        int kk  = idx >> 5;
        int cc  = (idx & 31) * 4;
        *(f4v*)&sk[kk][cc] = *(const f4v*)(W + (size_t)(kt + kk) * C_OUT + cc);
      }
      __syncthreads();
      #pragma unroll
      for (int k = 0; k < 32; k += 4) {
        f4v a[4];
        float2 b[4];
        #pragma unroll
        for (int q = 0; q < 4; ++q) a[q] = *(const f4v*)&sx[r0 + q][k];
        #pragma unroll
        for (int q = 0; q < 4; ++q) b[q] = *(const float2*)&sk[k + q][c0];
        #pragma unroll
        for (int i = 0; i < 4; ++i) {
          acc[i][0] += a[i][0] * b[0].x; acc[i][1] += a[i][0] * b[0].y;
          acc[i][0] += a[i][1] * b[1].x; acc[i][1] += a[i][1] * b[1].y;
          acc[i][0] += a[i][2] * b[2].x; acc[i][1] += a[i][2] * b[2].y;
          acc[i][0] += a[i][3] * b[3].x; acc[i][1] += a[i][3] * b[3].y;
        }
      }
      __syncthreads();
    }

    #pragma unroll
    for (int i = 0; i < 4; ++i)
      *(float2*)(ft + (size_t)(row0 + r0 + i) * C_OUT + c0) =
          make_float2(acc[i][0], acc[i][1]);

    float2 as = *(const float2*)(att_src + c0);
    float2 ad = *(const float2*)(att_dst + c0);
    #pragma unroll
    for (int i = 0; i < 4; ++i) {
      float ps = acc[i][0] * as.x + acc[i][1] * as.y;
      float pd = acc[i][0] * ad.x + acc[i][1] * ad.y;
      #pragma unroll
      for (int off = 32; off > 0; off >>= 1) {
        ps += __shfl_xor(ps, off);
        pd += __shfl_xor(pd, off);
      }
      if (lane == 0) {
        asrc[row0 + r0 + i] = ps;
        adst[row0 + r0 + i] = pd;
      }
    }

    float* scp = &sx[0][0];
    float s0 = acc[0][0] + acc[1][0] + acc[2][0] + acc[3][0];
    float s1 = acc[0][1] + acc[1][1] + acc[2][1] + acc[3][1];
    *(float2*)&scp[rg * 128 + c0] = make_float2(s0, s1);
    __syncthreads();
    if (tid < 128) {
      float s = 0.f;
      #pragma unroll
      for (int q = 0; q < 8; ++q) s += scp[q * 128 + tid];
      Spart[(size_t)gb * 128 + tid] = s;
    }
  } else {
    // ---------------- adj role ----------------
    const int ab   = bid - (bid + 1) / 5;  // 0..1023
    const int lane = tid & 63;
    const int wv   = tid >> 6;
    const int row  = ab * 8 + wv;
    const f4v* rp  = (const f4v*)(adj + (size_t)row * N_NODES);
    unsigned short* er = elist + (size_t)row * CSR_CAP;

    int base = 0;
    for (int cb = 0; cb < 32; cb += 8) {
      f4v v[8];
      #pragma unroll
      for (int q = 0; q < 8; ++q)
        v[q] = __builtin_nontemporal_load(&rp[(cb + q) * 64 + lane]);
      #pragma unroll
      for (int q = 0; q < 8; ++q) {
        const int colb = (cb + q) * 256 + lane * 4;
        unsigned long long b0 = __ballot(v[q][0] != 0.f);
        unsigned long long b1 = __ballot(v[q][1] != 0.f);
        unsigned long long b2 = __ballot(v[q][2] != 0.f);
        unsigned long long b3 = __ballot(v[q][3] != 0.f);
        int o = base + lane_lt_popc(b0) + lane_lt_popc(b1)
                     + lane_lt_popc(b2) + lane_lt_popc(b3);
        if ((b0 >> lane) & 1ull) { if (o < CSR_CAP) er[o] = (unsigned short)(colb + 0); ++o; }
        if ((b1 >> lane) & 1ull) { if (o < CSR_CAP) er[o] = (unsigned short)(colb + 1); ++o; }
        if ((b2 >> lane) & 1ull) { if (o < CSR_CAP) er[o] = (unsigned short)(colb + 2); ++o; }
        if ((b3 >> lane) & 1ull) { if (o < CSR_CAP) er[o] = (unsigned short)(colb + 3); ++o; }
        base += __popcll(b0) + __popcll(b1) + __popcll(b2) + __popcll(b3);
      }
    }
    if (lane == 0) counts[row] = base < CSR_CAP ? base : CSR_CAP;
  }
}

// ---------------------------------------------------------------------------
// Parallel colsum: block c sums Spart[0..255][c]. 128 blocks x 256 thr.
// Deterministic fixed-tree (shfl butterfly + 4-term wave combine).
// ---------------------------------------------------------------------------
__global__ void __launch_bounds__(256) colsum_par_kernel(
    const float* __restrict__ Spart, float* __restrict__ S)
{
  __shared__ float wpart[4];
  const int c = blockIdx.x;
  const int t = threadIdx.x;
  const int lane = t & 63, w = t >> 6;
  float v = Spart[(size_t)t * 128 + c];
  #pragma unroll
  for (int off = 32; off > 0; off >>= 1) v += __shfl_xor(v, off);
  if (lane == 0) wpart[w] = v;
  __syncthreads();
  if (t == 0) S[c] = wpart[0] + wpart[1] + wpart[2] + wpart[3];
}

// ---------------------------------------------------------------------------
// Gather kernel [byte-identical to round 4/5]
// ---------------------------------------------------------------------------
__global__ void __launch_bounds__(512) gat_gather_kernel(
    const int* __restrict__ counts, const unsigned short* __restrict__ elist,
    const float* __restrict__ ft, const float* __restrict__ asrc,
    const float* __restrict__ adst, const float* __restrict__ S,
    float* __restrict__ out)
{
  __shared__ int   sj[8][CSR_CAP];
  __shared__ float sw[8][CSR_CAP];

  const int lane = threadIdx.x & 63;
  const int wv   = threadIdx.x >> 6;
  const int row  = blockIdx.x * 8 + wv;
  const int cnt  = counts[row];
  const float ai = asrc[row];
  const unsigned short* er = elist + (size_t)row * CSR_CAP;

  float dsum = 0.f;
  for (int e = lane; e < cnt; e += 64) {
    int j = er[e];
    float s = ai + adst[j];
    float l = s < 0.f ? NEG_SLOPE * s : s;
    float w = expf(l);
    sj[wv][e] = j;
    sw[wv][e] = w - 1.0f;
    dsum += w;
  }
  #pragma unroll
  for (int off = 32; off > 0; off >>= 1) dsum += __shfl_xor(dsum, off);
  const float denom = (float)(N_NODES - cnt) + dsum;

  __syncthreads();

  float2 acc = make_float2(0.f, 0.f);
  const float2* ft2 = (const float2*)ft;
  int e = 0;
  for (; e + 4 <= cnt; e += 4) {
    int   j0 = sj[wv][e+0], j1 = sj[wv][e+1], j2 = sj[wv][e+2], j3 = sj[wv][e+3];
    float w0 = sw[wv][e+0], w1 = sw[wv][e+1], w2 = sw[wv][e+2], w3 = sw[wv][e+3];
    float2 f0 = ft2[(size_t)j0 * 64 + lane];
    float2 f1 = ft2[(size_t)j1 * 64 + lane];
    float2 f2 = ft2[(size_t)j2 * 64 + lane];
    float2 f3 = ft2[(size_t)j3 * 64 + lane];
    acc.x += w0 * f0.x; acc.y += w0 * f0.y;
    acc.x += w1 * f1.x; acc.y += w1 * f1.y;
    acc.x += w2 * f2.x; acc.y += w2 * f2.y;
    acc.x += w3 * f3.x; acc.y += w3 * f3.y;
  }
  for (; e < cnt; ++e) {
    int   j = sj[wv][e];
    float w = sw[wv][e];
    float2 f = ft2[(size_t)j * 64 + lane];
    acc.x += w * f.x; acc.y += w * f.y;
  }

  float2 sv = ((const float2*)S)[lane];
  float ox = (sv.x + acc.x) / denom;
  float oy = (sv.y + acc.y) / denom;
  ox = ox > 0.f ? ox : expm1f(ox);
  oy = oy > 0.f ? oy : expm1f(oy);
  ((float2*)out)[(size_t)row * 64 + lane] = make_float2(ox, oy);
}

// ---------------------------------------------------------------------------
extern "C" void kernel_launch(void* const* d_in, const int* in_sizes, int n_in,
                              void* d_out, int out_size, void* d_ws, size_t ws_size,
                              hipStream_t stream)
{
  const float* X       = (const float*)d_in[0];   // features 8192x512
  const float* adj     = (const float*)d_in[1];   // adjacency 8192x8192
  const float* W       = (const float*)d_in[2];   // kernel 512x128
  const float* att_src = (const float*)d_in[3];   // 128
  const float* att_dst = (const float*)d_in[4];   // 128
  float* out = (float*)d_out;

  float* ws    = (float*)d_ws;
  float* ft    = ws;                                   // 8192*128
  float* asrc  = ft + (size_t)N_NODES * C_OUT;         // 8192
  float* adst  = asrc + N_NODES;                       // 8192
  float* Spart = adst + N_NODES;                       // 256*128
  float* S     = Spart + 256 * 128;                    // 128
  int*   counts = (int*)(S + 128);                     // 8192
  unsigned short* elist = (unsigned short*)(counts + N_NODES); // 8192*128 u16

  fat_kernel<<<1280, 512, 0, stream>>>(adj, counts, elist,
                                       X, W, att_src, att_dst,
                                       ft, asrc, adst, Spart);
  colsum_par_kernel<<<128, 256, 0, stream>>>(Spart, S);
  gat_gather_kernel<<<N_NODES / 8, 512, 0, stream>>>(counts, elist, ft,
                                                     asrc, adst, S, out);
}

// Round 7
// 87.259 us; speedup vs baseline: 2.5145x; 1.1414x over previous
//
#include <hip/hip_runtime.h>
#include <hip/hip_bf16.h>
#include <hip/hip_fp16.h>
#include <math.h>

#define N_NODES 8192
#define HALF_N  4096
#define F_IN    512
#define C_OUT   128
#define CSR_CAP 128
#define NEG_SLOPE 0.2f

typedef float f4v __attribute__((ext_vector_type(4)));

__device__ __forceinline__ int lane_lt_popc(unsigned long long m) {
  return __builtin_amdgcn_mbcnt_hi((unsigned)(m >> 32),
         __builtin_amdgcn_mbcnt_lo((unsigned)m, 0u));
}

// ---------------------------------------------------------------------------
// K1: 768 blocks.  bid%3==2 -> gemm role (256 blocks, rows*32 of ft16 +
// asrc/adst + Spart).  else -> adj-scan role (512 blocks, rows [0,4096),
// elist/counts to HBM for K3).
// ---------------------------------------------------------------------------
__global__ void __launch_bounds__(512) fat1_kernel(
    const float* __restrict__ adj, int* __restrict__ counts,
    unsigned short* __restrict__ elist,
    const float* __restrict__ X, const float* __restrict__ W,
    const float* __restrict__ att_src, const float* __restrict__ att_dst,
    __half* __restrict__ ft16, float* __restrict__ asrc,
    float* __restrict__ adst, float* __restrict__ Spart)
{
  __shared__ float sx[32][36];
  __shared__ float sk[32][132];

  const int bid = blockIdx.x;
  const int tid = threadIdx.x;

  if ((bid % 3) == 2) {
    // ---------------- gemm role ----------------
    const int gb   = bid / 3;              // 0..255
    const int row0 = gb * 32;
    const int rg   = tid >> 6;
    const int r0   = rg * 4;
    const int lane = tid & 63;
    const int c0   = lane * 2;

    float acc[4][2] = {};

    for (int kt = 0; kt < F_IN; kt += 32) {
      if (tid < 256) {
        int row = tid >> 3, kv = (tid & 7) * 4;
        f4v v = *(const f4v*)(X + (size_t)(row0 + row) * F_IN + kt + kv);
        *(f4v*)&sx[row][kv] = v;
      }
      #pragma unroll
      for (int q = 0; q < 2; ++q) {
        int idx = q * 512 + tid;
        int kk  = idx >> 5;
        int cc  = (idx & 31) * 4;
        *(f4v*)&sk[kk][cc] = *(const f4v*)(W + (size_t)(kt + kk) * C_OUT + cc);
      }
      __syncthreads();
      #pragma unroll
      for (int k = 0; k < 32; k += 4) {
        f4v a[4];
        float2 b[4];
        #pragma unroll
        for (int q = 0; q < 4; ++q) a[q] = *(const f4v*)&sx[r0 + q][k];
        #pragma unroll
        for (int q = 0; q < 4; ++q) b[q] = *(const float2*)&sk[k + q][c0];
        #pragma unroll
        for (int i = 0; i < 4; ++i) {
          acc[i][0] += a[i][0] * b[0].x; acc[i][1] += a[i][0] * b[0].y;
          acc[i][0] += a[i][1] * b[1].x; acc[i][1] += a[i][1] * b[1].y;
          acc[i][0] += a[i][2] * b[2].x; acc[i][1] += a[i][2] * b[2].y;
          acc[i][0] += a[i][3] * b[3].x; acc[i][1] += a[i][3] * b[3].y;
        }
      }
      __syncthreads();
    }

    // ft in fp16 (gather is the only consumer)
    #pragma unroll
    for (int i = 0; i < 4; ++i) {
      __half2 h = __floats2half2_rn(acc[i][0], acc[i][1]);
      ((__half2*)ft16)[(size_t)(row0 + r0 + i) * 64 + lane] = h;
    }

    float2 as = *(const float2*)(att_src + c0);
    float2 ad = *(const float2*)(att_dst + c0);
    #pragma unroll
    for (int i = 0; i < 4; ++i) {
      float ps = acc[i][0] * as.x + acc[i][1] * as.y;
      float pd = acc[i][0] * ad.x + acc[i][1] * ad.y;
      #pragma unroll
      for (int off = 32; off > 0; off >>= 1) {
        ps += __shfl_xor(ps, off);
        pd += __shfl_xor(pd, off);
      }
      if (lane == 0) {
        asrc[row0 + r0 + i] = ps;
        adst[row0 + r0 + i] = pd;
      }
    }

    float* scp = &sx[0][0];
    float s0 = acc[0][0] + acc[1][0] + acc[2][0] + acc[3][0];
    float s1 = acc[0][1] + acc[1][1] + acc[2][1] + acc[3][1];
    *(float2*)&scp[rg * 128 + c0] = make_float2(s0, s1);
    __syncthreads();
    if (tid < 128) {
      float s = 0.f;
      #pragma unroll
      for (int q = 0; q < 8; ++q) s += scp[q * 128 + tid];
      Spart[(size_t)gb * 128 + tid] = s;
    }
  } else {
    // ---------------- adj-scan role: rows [0,4096) ----------------
    const int ab   = bid - bid / 3;        // 0..511
    const int lane = tid & 63;
    const int wv   = tid >> 6;
    const int row  = ab * 8 + wv;
    const f4v* rp  = (const f4v*)(adj + (size_t)row * N_NODES);
    unsigned short* er = elist + (size_t)row * CSR_CAP;

    int base = 0;
    for (int cb = 0; cb < 32; cb += 8) {
      f4v v[8];
      #pragma unroll
      for (int q = 0; q < 8; ++q)
        v[q] = __builtin_nontemporal_load(&rp[(cb + q) * 64 + lane]);
      #pragma unroll
      for (int q = 0; q < 8; ++q) {
        const int colb = (cb + q) * 256 + lane * 4;
        unsigned long long b0 = __ballot(v[q][0] != 0.f);
        unsigned long long b1 = __ballot(v[q][1] != 0.f);
        unsigned long long b2 = __ballot(v[q][2] != 0.f);
        unsigned long long b3 = __ballot(v[q][3] != 0.f);
        int o = base + lane_lt_popc(b0) + lane_lt_popc(b1)
                     + lane_lt_popc(b2) + lane_lt_popc(b3);
        if ((b0 >> lane) & 1ull) { if (o < CSR_CAP) er[o] = (unsigned short)(colb + 0); ++o; }
        if ((b1 >> lane) & 1ull) { if (o < CSR_CAP) er[o] = (unsigned short)(colb + 1); ++o; }
        if ((b2 >> lane) & 1ull) { if (o < CSR_CAP) er[o] = (unsigned short)(colb + 2); ++o; }
        if ((b3 >> lane) & 1ull) { if (o < CSR_CAP) er[o] = (unsigned short)(colb + 3); ++o; }
        base += __popcll(b0) + __popcll(b1) + __popcll(b2) + __popcll(b3);
      }
    }
    if (lane == 0) counts[row] = base < CSR_CAP ? base : CSR_CAP;
  }
}

// ---------------------------------------------------------------------------
// colsum: block c sums Spart[0..255][c].
// ---------------------------------------------------------------------------
__global__ void __launch_bounds__(256) colsum_par_kernel(
    const float* __restrict__ Spart, float* __restrict__ S)
{
  __shared__ float wpart[4];
  const int c = blockIdx.x;
  const int t = threadIdx.x;
  const int lane = t & 63, w = t >> 6;
  float v = Spart[(size_t)t * 128 + c];
  #pragma unroll
  for (int off = 32; off > 0; off >>= 1) v += __shfl_xor(v, off);
  if (lane == 0) wpart[w] = v;
  __syncthreads();
  if (t == 0) S[c] = wpart[0] + wpart[1] + wpart[2] + wpart[3];
}

// ---------------------------------------------------------------------------
// K2: adj-scan rows [4096,8192) with gather FUSED into the same wave.
// elist stays in per-wave LDS (never touches HBM). All state wave-local:
// no barriers at all.
// ---------------------------------------------------------------------------
__global__ void __launch_bounds__(512) scan_gather_kernel(
    const float* __restrict__ adj, const __half* __restrict__ ft16,
    const float* __restrict__ asrc, const float* __restrict__ adst,
    const float* __restrict__ S, float* __restrict__ out)
{
  __shared__ unsigned short el[8][CSR_CAP];
  __shared__ float swt[8][CSR_CAP];

  const int lane = threadIdx.x & 63;
  const int wv   = threadIdx.x >> 6;
  const int row  = HALF_N + blockIdx.x * 8 + wv;
  const f4v* rp  = (const f4v*)(adj + (size_t)row * N_NODES);

  // ---- scan (identical pattern, edge list -> LDS)
  int base = 0;
  for (int cb = 0; cb < 32; cb += 8) {
    f4v v[8];
    #pragma unroll
    for (int q = 0; q < 8; ++q)
      v[q] = __builtin_nontemporal_load(&rp[(cb + q) * 64 + lane]);
    #pragma unroll
    for (int q = 0; q < 8; ++q) {
      const int colb = (cb + q) * 256 + lane * 4;
      unsigned long long b0 = __ballot(v[q][0] != 0.f);
      unsigned long long b1 = __ballot(v[q][1] != 0.f);
      unsigned long long b2 = __ballot(v[q][2] != 0.f);
      unsigned long long b3 = __ballot(v[q][3] != 0.f);
      int o = base + lane_lt_popc(b0) + lane_lt_popc(b1)
                   + lane_lt_popc(b2) + lane_lt_popc(b3);
      if ((b0 >> lane) & 1ull) { if (o < CSR_CAP) el[wv][o] = (unsigned short)(colb + 0); ++o; }
      if ((b1 >> lane) & 1ull) { if (o < CSR_CAP) el[wv][o] = (unsigned short)(colb + 1); ++o; }
      if ((b2 >> lane) & 1ull) { if (o < CSR_CAP) el[wv][o] = (unsigned short)(colb + 2); ++o; }
      if ((b3 >> lane) & 1ull) { if (o < CSR_CAP) el[wv][o] = (unsigned short)(colb + 3); ++o; }
      base += __popcll(b0) + __popcll(b1) + __popcll(b2) + __popcll(b3);
    }
  }
  const int cnt = base < CSR_CAP ? base : CSR_CAP;
  const float ai = asrc[row];

  // ---- softmax weights + denom (wave-local, no barrier)
  float dsum = 0.f;
  for (int e = lane; e < cnt; e += 64) {
    int j = el[wv][e];
    float s = ai + adst[j];
    float l = s < 0.f ? NEG_SLOPE * s : s;
    float w = expf(l);
    swt[wv][e] = w - 1.0f;
    dsum += w;
  }
  #pragma unroll
  for (int off = 32; off > 0; off >>= 1) dsum += __shfl_xor(dsum, off);
  const float denom = (float)(N_NODES - cnt) + dsum;

  // ---- gather (fp16 ft, L2-resident)
  float2 acc = make_float2(0.f, 0.f);
  const __half2* f2 = (const __half2*)ft16;
  int e = 0;
  for (; e + 4 <= cnt; e += 4) {
    int   j0 = el[wv][e+0], j1 = el[wv][e+1], j2 = el[wv][e+2], j3 = el[wv][e+3];
    float w0 = swt[wv][e+0], w1 = swt[wv][e+1], w2 = swt[wv][e+2], w3 = swt[wv][e+3];
    float2 f0 = __half22float2(f2[(size_t)j0 * 64 + lane]);
    float2 f1 = __half22float2(f2[(size_t)j1 * 64 + lane]);
    float2 f2v = __half22float2(f2[(size_t)j2 * 64 + lane]);
    float2 f3 = __half22float2(f2[(size_t)j3 * 64 + lane]);
    acc.x += w0 * f0.x;  acc.y += w0 * f0.y;
    acc.x += w1 * f1.x;  acc.y += w1 * f1.y;
    acc.x += w2 * f2v.x; acc.y += w2 * f2v.y;
    acc.x += w3 * f3.x;  acc.y += w3 * f3.y;
  }
  for (; e < cnt; ++e) {
    int   j = el[wv][e];
    float w = swt[wv][e];
    float2 f = __half22float2(f2[(size_t)j * 64 + lane]);
    acc.x += w * f.x; acc.y += w * f.y;
  }

  float2 sv = ((const float2*)S)[lane];
  float ox = (sv.x + acc.x) / denom;
  float oy = (sv.y + acc.y) / denom;
  ox = ox > 0.f ? ox : expm1f(ox);
  oy = oy > 0.f ? oy : expm1f(oy);
  ((float2*)out)[(size_t)row * 64 + lane] = make_float2(ox, oy);
}

// ---------------------------------------------------------------------------
// K3: gather-only for rows [0,4096) from K1's HBM CSR. fp16 ft.
// ---------------------------------------------------------------------------
__global__ void __launch_bounds__(512) gather1_kernel(
    const int* __restrict__ counts, const unsigned short* __restrict__ elist,
    const __half* __restrict__ ft16, const float* __restrict__ asrc,
    const float* __restrict__ adst, const float* __restrict__ S,
    float* __restrict__ out)
{
  __shared__ int   sj[8][CSR_CAP];
  __shared__ float sw[8][CSR_CAP];

  const int lane = threadIdx.x & 63;
  const int wv   = threadIdx.x >> 6;
  const int row  = blockIdx.x * 8 + wv;
  const int cnt  = counts[row];
  const float ai = asrc[row];
  const unsigned short* er = elist + (size_t)row * CSR_CAP;

  float dsum = 0.f;
  for (int e = lane; e < cnt; e += 64) {
    int j = er[e];
    float s = ai + adst[j];
    float l = s < 0.f ? NEG_SLOPE * s : s;
    float w = expf(l);
    sj[wv][e] = j;
    sw[wv][e] = w - 1.0f;
    dsum += w;
  }
  #pragma unroll
  for (int off = 32; off > 0; off >>= 1) dsum += __shfl_xor(dsum, off);
  const float denom = (float)(N_NODES - cnt) + dsum;

  __syncthreads();

  float2 acc = make_float2(0.f, 0.f);
  const __half2* f2 = (const __half2*)ft16;
  int e = 0;
  for (; e + 4 <= cnt; e += 4) {
    int   j0 = sj[wv][e+0], j1 = sj[wv][e+1], j2 = sj[wv][e+2], j3 = sj[wv][e+3];
    float w0 = sw[wv][e+0], w1 = sw[wv][e+1], w2 = sw[wv][e+2], w3 = sw[wv][e+3];
    float2 f0 = __half22float2(f2[(size_t)j0 * 64 + lane]);
    float2 f1 = __half22float2(f2[(size_t)j1 * 64 + lane]);
    float2 f2v = __half22float2(f2[(size_t)j2 * 64 + lane]);
    float2 f3 = __half22float2(f2[(size_t)j3 * 64 + lane]);
    acc.x += w0 * f0.x;  acc.y += w0 * f0.y;
    acc.x += w1 * f1.x;  acc.y += w1 * f1.y;
    acc.x += w2 * f2v.x; acc.y += w2 * f2v.y;
    acc.x += w3 * f3.x;  acc.y += w3 * f3.y;
  }
  for (; e < cnt; ++e) {
    int   j = sj[wv][e];
    float w = sw[wv][e];
    float2 f = __half22float2(f2[(size_t)j * 64 + lane]);
    acc.x += w * f.x; acc.y += w * f.y;
  }

  float2 sv = ((const float2*)S)[lane];
  float ox = (sv.x + acc.x) / denom;
  float oy = (sv.y + acc.y) / denom;
  ox = ox > 0.f ? ox : expm1f(ox);
  oy = oy > 0.f ? oy : expm1f(oy);
  ((float2*)out)[(size_t)row * 64 + lane] = make_float2(ox, oy);
}

// ---------------------------------------------------------------------------
extern "C" void kernel_launch(void* const* d_in, const int* in_sizes, int n_in,
                              void* d_out, int out_size, void* d_ws, size_t ws_size,
                              hipStream_t stream)
{
  const float* X       = (const float*)d_in[0];   // features 8192x512
  const float* adj     = (const float*)d_in[1];   // adjacency 8192x8192
  const float* W       = (const float*)d_in[2];   // kernel 512x128
  const float* att_src = (const float*)d_in[3];   // 128
  const float* att_dst = (const float*)d_in[4];   // 128
  float* out = (float*)d_out;

  float* ws    = (float*)d_ws;
  float* asrc  = ws;                                    // 8192
  float* adst  = asrc + N_NODES;                        // 8192
  float* Spart = adst + N_NODES;                        // 256*128
  float* S     = Spart + 256 * 128;                     // 128
  int*   counts = (int*)(S + 128);                      // 4096 (half 1 only)
  __half* ft16 = (__half*)(counts + HALF_N);            // 8192*128 fp16
  unsigned short* elist =
      (unsigned short*)(ft16 + (size_t)N_NODES * C_OUT); // 4096*128 u16

  fat1_kernel<<<768, 512, 0, stream>>>(adj, counts, elist,
                                       X, W, att_src, att_dst,
                                       ft16, asrc, adst, Spart);
  colsum_par_kernel<<<128, 256, 0, stream>>>(Spart, S);
  scan_gather_kernel<<<HALF_N / 8, 512, 0, stream>>>(adj, ft16, asrc, adst,
                                                     S, out);
  gather1_kernel<<<HALF_N / 8, 512, 0, stream>>>(counts, elist, ft16,
                                                 asrc, adst, S, out);
}